// Round 1
// baseline (99.191 us; speedup 1.0000x reference)
//
#include <hip/hip_runtime.h>
#include <hip/hip_bf16.h>

#define BATCH 2048
#define IDIM  256
#define ODIM  64
#define GRIDN 300

typedef __bf16 bf16x8 __attribute__((ext_vector_type(8)));
typedef float  f32x16 __attribute__((ext_vector_type(16)));
typedef unsigned int uint4v __attribute__((ext_vector_type(4)));

#define AS1 __attribute__((address_space(1)))
#define AS3 __attribute__((address_space(3)))

union ABFrag {
    unsigned short us[8];
    unsigned int   u32[4];
    uint4v         u4;
    bf16x8         bv;
};

__device__ __forceinline__ unsigned short f2bf(float f) {
    union { __hip_bfloat16 h; unsigned short u; } v;
    v.h = __float2bfloat16(f);   // RNE; compiler can fuse pairs into v_cvt_pk_bf16_f32
    return v.u;
}

// ---------------------------------------------------------------------------
// Prep: fouriercoeffs [2][64][256][300] f32  ->  WP bf16 chunks of 4KB:
//   WP[isplit(16)][g(300)] chunk, in-chunk byte = (j*64 + kl*2) ^ ((j>>1)&3)<<5
//   kl = il*2 + t  (il = i%16, t: 0=cos weight, 1=sin weight)
// Reads coalesced along g; 4B dword writes (cos|sin<<16) merged in L2.
// ---------------------------------------------------------------------------
__global__ __launch_bounds__(256) void fkan_prep(const float* __restrict__ fc,
                                                 char* __restrict__ wp) {
    const int j  = blockIdx.x & 63;
    const int ib = blockIdx.x >> 6;      // i-split
    const int il = threadIdx.x >> 4;     // 0..15
    const int gp = threadIdx.x & 15;
    const int i  = ib * 16 + il;
    const float* crow = fc + ((size_t)j * IDIM + i) * GRIDN;               // t=0
    const float* srow = crow + (size_t)ODIM * IDIM * GRIDN;                // t=1
    const unsigned swz  = ((unsigned)(j >> 1) & 3u) << 5;
    const unsigned base = (unsigned)(j * 64 + il * 4) ^ swz;
    #pragma unroll
    for (int p = 0; p < 5; ++p) {
        const int g0 = p * 64 + gp * 4;
        if (g0 < GRIDN) {   // 300 % 4 == 0 -> full float4 always in-range
            float4 cv = *(const float4*)(crow + g0);
            float4 sv = *(const float4*)(srow + g0);
            float cfa[4] = {cv.x, cv.y, cv.z, cv.w};
            float sfa[4] = {sv.x, sv.y, sv.z, sv.w};
            #pragma unroll
            for (int d = 0; d < 4; ++d) {
                unsigned int dw = (unsigned)f2bf(cfa[d]) | ((unsigned)f2bf(sfa[d]) << 16);
                size_t chunk = ((size_t)ib * GRIDN + (g0 + d)) * 4096;
                *(unsigned int*)(wp + chunk + base) = dw;
            }
        }
    }
}

// ---------------------------------------------------------------------------
// Main: grid 1024 = 8 xcd * (2 isplit * 2 ghalf * 32 mtile); block 256 = 4 waves.
// Wave (wm,wn) owns a 32x32 output tile of the block's 64x64.
// Per lane: 8 (row,i) phase states advanced by complex recurrence each g.
// B staged 4KB/g via global_load_lds, double-buffered, XOR-swizzled ds_read_b128.
// Split-K partials -> unsafeAtomicAdd (d_out zeroed by memset each launch).
// ---------------------------------------------------------------------------
__global__ __launch_bounds__(256, 4) void fkan_main(const float* __restrict__ x,
                                                    const char* __restrict__ wp,
                                                    float* __restrict__ out) {
    __shared__ alignas(16) char lds[8192];

    const int bid    = blockIdx.x;
    const int xcd    = bid & 7;
    const int local  = bid >> 3;
    const int isplit = xcd * 2 + (local & 1);   // same-isplit blocks share an XCD L2
    const int ghalf  = (local >> 1) & 1;
    const int mtile  = local >> 2;
    const int g_begin = ghalf * 150;

    const int tid  = threadIdx.x;
    const int wave = tid >> 6;
    const int lane = tid & 63;
    const int wm   = wave >> 1, wn = wave & 1;
    const int l31  = lane & 31;
    const int kgrp = lane >> 5;
    const int row  = mtile * 64 + wm * 32 + l31;   // batch row (A-side lane row)
    const int jcol = wn * 32 + l31;                // output col (B-side lane col)

    // --- init 8 recurrence states: il = h*8 + kgrp*4 + p -----------------
    float stc[8], sts[8], bcs[8], bss[8];
    const float* xrow = x + (size_t)row * IDIM + isplit * 16;
    #pragma unroll
    for (int h = 0; h < 2; ++h) {
        #pragma unroll
        for (int p = 0; p < 4; ++p) {
            const int ss = h * 4 + p;
            const int il = h * 8 + kgrp * 4 + p;
            const float xv = xrow[il];
            float sb, cb;
            __sincosf(xv, &sb, &cb);
            bcs[ss] = cb; bss[ss] = sb;
            float s0 = sb, c0 = cb;
            if (g_begin != 0) __sincosf((float)(g_begin + 1) * xv, &s0, &c0);
            stc[ss] = c0; sts[ss] = s0;
        }
    }

    const unsigned swz = ((unsigned)(jcol >> 1) & 3u) << 5;
    const unsigned a1  = ((unsigned)(jcol * 64 + kgrp * 16)) ^ swz;        // kl 0..15
    const unsigned a2  = ((unsigned)(jcol * 64 + 32 + kgrp * 16)) ^ swz;   // kl 16..31

    const char* wbase = wp + ((size_t)isplit * GRIDN + g_begin) * 4096
                           + wave * 1024 + lane * 16;

    // prologue: stage g-chunk 0 into buf0
    __builtin_amdgcn_global_load_lds((const AS1 unsigned int*)wbase,
                                     (AS3 unsigned int*)(lds + wave * 1024),
                                     16, 0, 0);
    __syncthreads();

    f32x16 acc = {0,0,0,0,0,0,0,0,0,0,0,0,0,0,0,0};

    #pragma unroll 2
    for (int it = 0; it < 150; ++it) {
        const int cur = it & 1;
        if (it + 1 < 150) {
            __builtin_amdgcn_global_load_lds(
                (const AS1 unsigned int*)(wbase + (size_t)(it + 1) * 4096),
                (AS3 unsigned int*)(lds + (cur ^ 1) * 4096 + wave * 1024),
                16, 0, 0);
        }
        ABFrag b1, b2, af1, af2;
        b1.u4 = *(const uint4v*)(lds + cur * 4096 + a1);
        b2.u4 = *(const uint4v*)(lds + cur * 4096 + a2);
        #pragma unroll
        for (int p = 0; p < 4; ++p) {
            af1.us[2*p]   = f2bf(stc[p]);     // kl even = cos
            af1.us[2*p+1] = f2bf(sts[p]);     // kl odd  = sin
            af2.us[2*p]   = f2bf(stc[4+p]);
            af2.us[2*p+1] = f2bf(sts[4+p]);
        }
        acc = __builtin_amdgcn_mfma_f32_32x32x16_bf16(af1.bv, b1.bv, acc, 0, 0, 0);
        acc = __builtin_amdgcn_mfma_f32_32x32x16_bf16(af2.bv, b2.bv, acc, 0, 0, 0);
        // advance phases for next g (angle addition; fp32, ~3e-4 rad drift @300)
        #pragma unroll
        for (int ss = 0; ss < 8; ++ss) {
            const float c = stc[ss], s = sts[ss];
            stc[ss] = c * bcs[ss] - s * bss[ss];
            sts[ss] = s * bcs[ss] + c * bss[ss];
        }
        __syncthreads();
    }

    // epilogue: D layout (32x32): col=lane&31, row=(r&3)+8*(r>>2)+4*(lane>>5)
    #pragma unroll
    for (int r = 0; r < 16; ++r) {
        const int orow = mtile * 64 + wm * 32 + (r & 3) + 8 * (r >> 2) + 4 * kgrp;
        unsafeAtomicAdd(out + (size_t)orow * ODIM + wn * 32 + l31, acc[r]);
    }
}

// ---------------------------------------------------------------------------
// Fallback (ws too small): exact fp32, one thread per (b,j). Slow but correct.
// ---------------------------------------------------------------------------
__global__ __launch_bounds__(256) void fkan_naive(const float* __restrict__ x,
                                                  const float* __restrict__ fc,
                                                  float* __restrict__ out) {
    const int j = blockIdx.x >> 3;
    const int b = (blockIdx.x & 7) * 256 + threadIdx.x;
    const float* xr = x + (size_t)b * IDIM;
    float acc = 0.f;
    for (int i = 0; i < IDIM; ++i) {
        const float xv = xr[i];
        float sb, cb;
        __sincosf(xv, &sb, &cb);
        float c = cb, s = sb;
        const float* wc = fc + ((size_t)j * IDIM + i) * GRIDN;
        const float* ws = wc + (size_t)ODIM * IDIM * GRIDN;
        for (int g = 0; g < GRIDN; ++g) {
            acc += c * wc[g] + s * ws[g];
            const float cn = c * cb - s * sb;
            s = s * cb + c * sb;
            c = cn;
        }
    }
    out[(size_t)b * ODIM + j] = acc;
}

extern "C" void kernel_launch(void* const* d_in, const int* in_sizes, int n_in,
                              void* d_out, int out_size, void* d_ws, size_t ws_size,
                              hipStream_t stream) {
    const float* x  = (const float*)d_in[0];
    const float* fc = (const float*)d_in[1];
    float* out = (float*)d_out;
    constexpr size_t WPB = 16ull * GRIDN * 4096;   // 19.66 MB bf16 weight image

    if (ws_size >= WPB) {
        hipMemsetAsync(d_out, 0, (size_t)out_size * sizeof(float), stream);
        fkan_prep<<<1024, 256, 0, stream>>>(fc, (char*)d_ws);
        fkan_main<<<1024, 256, 0, stream>>>(x, (const char*)d_ws, out);
    } else {
        fkan_naive<<<512, 256, 0, stream>>>(x, fc, out);
    }
}